// Round 9
// baseline (1554.406 us; speedup 1.0000x reference)
//
#include <hip/hip_runtime.h>
#include <hip/hip_bf16.h>

// Problem constants
#define BB 64
#define TT 256
#define HH 256
#define LL 15
#define E300 300
#define KPAD 608              // 600 padded to multiple of 32 (19 k-steps of 32)
#define NG 2048               // 2 directions * 4H gates
#define MROWS 16384           // B*T

typedef float  floatx4 __attribute__((ext_vector_type(4)));
typedef float  floatx2 __attribute__((ext_vector_type(2)));
typedef __bf16 bf16x8  __attribute__((ext_vector_type(8)));

// ALL float tensor inputs are float32 (per reference; proven rounds 1-3).
// R4: L2-fetch theory. R5-R8: >64-VGPR designs spill; budget is HARD 64.
// R10: three-tier residency (4 uint4 regs + 8 LDS + 4 L2-streamed) killed the
//      spill (VGPR 52, FETCH 3.4e4 KB) -> 1228us. BUT R0 (all-streamed) was
//      1187us: weight traffic was NEVER the limit. k_lstm is per-step-LATENCY
//      bound at ~4.7us/step: 2 barriers (16-wave skew + vmcnt drain), red[]
//      LDS round trip, epilogue on only 4/16 waves with libm tanhf.
// R11: restructure the step. lane=(q*16+jj) -> 4 k-partials of a column in
//      one wave -> shfl_xor reduce (red[] + barrier1 DELETED); epilogue on
//      all 16 waves (redundant across q; c identical); ONE barrier/step
//      (lgkmcnt-only wait + builtin s_barrier, no vmcnt drain -> Hout stores
//      fly); double-buffered h; exp/rcp sigmoid+tanh. Residency per R10.
// (R8 round was an infra failure -- "container failed twice" -- resubmitting
//  R11 with the barrier expressed via the HW-proven builtin idiom.)

// ---------------- prep kernels ----------------

// X[row][0..299]=bf16(emb[id]), [300..599]=bf16(soft_emb[sid]), [600..607]=0
__global__ void k_embed(const int* __restrict__ ids, const int* __restrict__ sids,
                        const float* __restrict__ emb,
                        const float* __restrict__ semb,
                        __hip_bfloat16* __restrict__ X) {
    int row = blockIdx.x;
    int id  = ids[row];
    int sid = sids[row];
    const float* e0 = emb  + (long)id  * E300;
    const float* e1 = semb + (long)sid * E300;
    __hip_bfloat16* xr = X + (long)row * KPAD;
    for (int c = threadIdx.x; c < KPAD; c += blockDim.x) {
        float v;
        if (c < 300)      v = e0[c];
        else if (c < 600) v = e1[c - 300];
        else              v = 0.f;
        xr[c] = __float2bfloat16(v);
    }
}

// Wcat[2048][608] GATE-INTERLEAVED: row r -> dir=r>>10, j=(r&1023)>>2, gate=r&3,
// source row = gate*256+j of Wih_dir. G then comes out as [row][dir][j][gate].
__global__ void k_wcat(const float* __restrict__ Wf,
                       const float* __restrict__ Wb,
                       __hip_bfloat16* __restrict__ Wcat) {
    int r = blockIdx.x;
    int dir = r >> 10, rr = r & 1023, j = rr >> 2, gate = rr & 3;
    const float* src = (dir ? Wb : Wf) + (long)(gate * 256 + j) * 600;
    __hip_bfloat16* dst = Wcat + (long)r * KPAD;
    for (int c = threadIdx.x; c < KPAD; c += blockDim.x)
        dst[c] = __float2bfloat16((c < 600) ? src[c] : 0.f);
}

// Wpk8[d][q][j][kk] (q=k>>6, kk=k&63): packed fp8 e4m3 x4 gates for (j, k=q*64+kk).
// byte g = fp8(16 * Whh_dir[g*256+j][k]).  Per-(d,q,j) the 64 kk-dwords are
// CONTIGUOUS: dwords 0..15 -> regs, 16..47 -> LDS, 48..63 -> per-step L2 stream.
__global__ void k_wpk(const float* __restrict__ Wf,
                      const float* __restrict__ Wb,
                      unsigned int* __restrict__ Wpk8) {
    int d = blockIdx.x >> 8;
    int k = blockIdx.x & 255;
    int j = threadIdx.x;
    const float* W = d ? Wb : Wf;
    float w0 = W[((long)(0 * 256 + j)) * 256 + k] * 16.f;
    float w1 = W[((long)(1 * 256 + j)) * 256 + k] * 16.f;
    float w2 = W[((long)(2 * 256 + j)) * 256 + k] * 16.f;
    float w3 = W[((long)(3 * 256 + j)) * 256 + k] * 16.f;
    int r = 0;
    r = __builtin_amdgcn_cvt_pk_fp8_f32(w0, w1, r, false);  // bytes 0,1 = i,f
    r = __builtin_amdgcn_cvt_pk_fp8_f32(w2, w3, r, true);   // bytes 2,3 = g,o
    Wpk8[(((long)d * 4 + (k >> 6)) * 256 + j) * 64 + (k & 63)] = (unsigned int)r;
}

// bias[dir][j4] = bih + bhh (fp32)
__global__ void k_bias(const float* __restrict__ bfi, const float* __restrict__ bfh,
                       const float* __restrict__ bbi, const float* __restrict__ bbh,
                       float* __restrict__ bias) {
    int i = blockIdx.x * blockDim.x + threadIdx.x;
    if (i < 2048) {
        int d = i >> 10, j = i & 1023;
        const float* b1 = d ? bbi : bfi;
        const float* b2 = d ? bbh : bfh;
        bias[i] = b1[j] + b2[j];
    }
}

// ---------------- input GEMM:  G[16384][2048] = X[16384][608] * Wcat[2048][608]^T ----------------
__global__ __launch_bounds__(256) void k_gemm(const __hip_bfloat16* __restrict__ A,
                                              const __hip_bfloat16* __restrict__ Bw,
                                              __hip_bfloat16* __restrict__ C) {
    __shared__ __align__(16) unsigned short As[128 * 40];  // 128 x 32, row stride 40 (pad)
    __shared__ __align__(16) unsigned short Bs[128 * 40];
    int bm = blockIdx.x, bn = blockIdx.y;
    int row0 = bm * 128, col0 = bn * 128;
    int tid = threadIdx.x;
    int wave = tid >> 6, lane = tid & 63;
    int wm = (wave >> 1) * 64, wn = (wave & 1) * 64;
    int l15 = lane & 15, quad = lane >> 4;
    floatx4 acc[4][4];
    #pragma unroll
    for (int i = 0; i < 4; ++i)
        #pragma unroll
        for (int j = 0; j < 4; ++j) acc[i][j] = (floatx4){0.f, 0.f, 0.f, 0.f};

    int r1 = tid >> 2, p1 = tid & 3;  // staging: chunk row / 16B-part

    for (int kk = 0; kk < KPAD; kk += 32) {
        uint4 a0 = *(const uint4*)(A  + ((long)(row0 + r1))      * KPAD + kk + p1 * 8);
        uint4 a1 = *(const uint4*)(A  + ((long)(row0 + 64 + r1)) * KPAD + kk + p1 * 8);
        uint4 b0 = *(const uint4*)(Bw + ((long)(col0 + r1))      * KPAD + kk + p1 * 8);
        uint4 b1 = *(const uint4*)(Bw + ((long)(col0 + 64 + r1)) * KPAD + kk + p1 * 8);
        *(uint4*)&As[r1 * 40 + p1 * 8]        = a0;
        *(uint4*)&As[(64 + r1) * 40 + p1 * 8] = a1;
        *(uint4*)&Bs[r1 * 40 + p1 * 8]        = b0;
        *(uint4*)&Bs[(64 + r1) * 40 + p1 * 8] = b1;
        __syncthreads();
        bf16x8 af[4], bfr[4];
        #pragma unroll
        for (int tm = 0; tm < 4; ++tm)
            af[tm] = *(const bf16x8*)&As[(wm + tm * 16 + l15) * 40 + quad * 8];
        #pragma unroll
        for (int tn = 0; tn < 4; ++tn)
            bfr[tn] = *(const bf16x8*)&Bs[(wn + tn * 16 + l15) * 40 + quad * 8];
        #pragma unroll
        for (int tm = 0; tm < 4; ++tm)
            #pragma unroll
            for (int tn = 0; tn < 4; ++tn)
                acc[tm][tn] = __builtin_amdgcn_mfma_f32_16x16x32_bf16(af[tm], bfr[tn], acc[tm][tn], 0, 0, 0);
        __syncthreads();
    }
    // C/D layout: m = quad*4 + reg, n = lane&15
    #pragma unroll
    for (int tm = 0; tm < 4; ++tm)
        #pragma unroll
        for (int tn = 0; tn < 4; ++tn) {
            int m0 = row0 + wm + tm * 16 + quad * 4;
            int n  = col0 + wn + tn * 16 + l15;
            #pragma unroll
            for (int r = 0; r < 4; ++r)
                C[((long)(m0 + r)) * NG + n] = __float2bfloat16(acc[tm][tn][r]);
        }
}

// ---------------- LSTM recurrence ----------------
// One block per (batch, direction), 1024 threads = 16 waves.
// Wave w owns columns j = w*16 .. w*16+15; lane = q*16+jj ->
// (k-quarter q, column j=w*16+jj). Each thread: 64-dword weight slice
// (4 uint4 regs / 8 uint4 LDS / 4 uint4 L2-streamed), partial k-sum ->
// shfl_xor(16,32) butterfly -> all lanes hold full gate sums -> epilogue
// in-wave (redundant across q), q==0 writes h. ONE barrier per step.
#define MAC1(w, hk) {                                                   \
    floatx2 wif = __builtin_amdgcn_cvt_pk_f32_fp8((w), false);          \
    floatx2 wgo = __builtin_amdgcn_cvt_pk_f32_fp8((w), true);           \
    floatx2 h2 = (floatx2){(hk), (hk)};                                 \
    aIF += h2 * wif;                                                    \
    aGO += h2 * wgo; }

#define MACW(W, base) {                                                 \
    floatx4 h4 = *(const floatx4*)&hq[(base)];                          \
    MAC1((W).x, h4[0]); MAC1((W).y, h4[1]);                             \
    MAC1((W).z, h4[2]); MAC1((W).w, h4[3]); }

// LDS half: group g covers k = 16+4g .. 19+4g; slot stride 64 entries (512 B)
#define MACL(g) {                                                       \
    floatx4 h4 = *(const floatx4*)&hq[16 + 4 * (g)];                    \
    unsigned long long wa = *(volatile const unsigned long long*)&Wl[(2 * (g)) * 64];     \
    unsigned long long wb = *(volatile const unsigned long long*)&Wl[(2 * (g) + 1) * 64]; \
    MAC1((unsigned)wa, h4[0]); MAC1((unsigned)(wa >> 32), h4[1]);       \
    MAC1((unsigned)wb, h4[2]); MAC1((unsigned)(wb >> 32), h4[3]); }

__device__ __forceinline__ float b2f(unsigned u) {
    union { unsigned i; float f; } v; v.i = u << 16; return v.f;
}
__device__ __forceinline__ float sigm_(float x) {
    return __builtin_amdgcn_rcpf(1.f + __expf(-x));
}
__device__ __forceinline__ float tanh_(float x) {
    return 2.f * __builtin_amdgcn_rcpf(1.f + __expf(-2.f * x)) - 1.f;
}

__global__ __launch_bounds__(1024)
void k_lstm(const __hip_bfloat16* __restrict__ G,    // [MROWS][2][256][4] gate-interleaved
            const unsigned int* __restrict__ Wpk8,   // [2][4][256][64] fp8x4
            const float* __restrict__ bias,          // [2][1024]
            const int* __restrict__ lengths,
            __hip_bfloat16* __restrict__ Hout) {     // [B][T][512]
    int dir = blockIdx.x & 1;
    int b   = blockIdx.x >> 1;
    int tid = threadIdx.x;
    int w    = tid >> 6;
    int lane = tid & 63;
    int q    = lane >> 4;       // k-quarter (lane bits 4-5)
    int jj   = lane & 15;
    int j    = w * 16 + jj;     // hidden column
    // padded h buffers: value h[k]/16 lives at [ (k>>6)*68 + (k&63) ]
    __shared__ __align__(16) float hsbuf[2][4 * 68];
    // W LDS tier: [w][slot 0..15][lane] b64 entries = 128 KB
    __shared__ __align__(16) unsigned long long Wlds[16 * 16 * 64];
    if (tid < 2 * 4 * 68) ((float*)hsbuf)[tid] = 0.f;
    int len = lengths[b];
    // per-thread weight slice: 64 contiguous dwords at wt[0..15] (uint4 units)
    const uint4* wt = (const uint4*)Wpk8 + (((long)dir * 4 + q) * 256 + j) * 16;
    // tier 1: kk 0..15 in 4 named uint4 regs
    uint4 W00 = wt[0], W01 = wt[1], W02 = wt[2], W03 = wt[3];
    // tier 2: kk 16..47 -> LDS, 16 b64 slots at [w][s][lane]
    unsigned long long* Wl = Wlds + (long)w * 16 * 64 + lane;
    #pragma unroll
    for (int i = 0; i < 8; ++i) {
        uint4 v = wt[4 + i];
        Wl[(2 * i) * 64]     = (unsigned long long)v.x | ((unsigned long long)v.y << 32);
        Wl[(2 * i + 1) * 64] = (unsigned long long)v.z | ((unsigned long long)v.w << 32);
    }
    // tier 3: kk 48..63 streamed from L2 every step (opaque address)
    unsigned long wsa = (unsigned long)(wt + 12);
    // bias: only q==0 lanes add it (pre-butterfly), once per column
    float bi = 0.f, bf_ = 0.f, bg = 0.f, bo = 0.f;
    if (q == 0) {
        const float* bs = bias + dir * 1024;
        bi = bs[j]; bf_ = bs[256 + j]; bg = bs[512 + j]; bo = bs[768 + j];
    }
    const __hip_bfloat16* Gb = G + ((long)b * TT) * NG + dir * 1024;
    float c = 0.f;
    int p = 0;
    __syncthreads();
    for (int t = 0; t < TT; ++t) {
        int tt = t;
        if (dir) tt = (t < len) ? (len - 1 - t) : t;
        // stream loads first (L2; hidden under reg/LDS MACs); opaque vs LICM
        unsigned long wsv = wsa;
        asm volatile("" : "+v"(wsv));
        const uint4* ws = (const uint4*)wsv;
        uint4 S0 = ws[0], S1 = ws[1], S2 = ws[2], S3 = ws[3];
        uint2 gp = (uint2){0u, 0u};
        if (q == 0)   // packed gate inputs (i,f,g,o) for column j: one 8B load
            gp = *(const uint2*)(Gb + (long)tt * NG + j * 4);
        const float* hq = hsbuf[p] + q * 68;
        floatx2 aIF = (floatx2){0.f, 0.f};
        floatx2 aGO = (floatx2){0.f, 0.f};
        MACW(W00, 0) MACW(W01, 4) MACW(W02, 8) MACW(W03, 12)
        MACL(0) MACL(1) MACL(2) MACL(3)
        MACL(4) MACL(5) MACL(6) MACL(7)
        MACW(S0, 48) MACW(S1, 52) MACW(S2, 56) MACW(S3, 60)
        if (q == 0) {   // bias + gate-input added exactly once per column
            aIF += (floatx2){bi + b2f(gp.x & 0xffffu), bf_ + b2f(gp.x >> 16)};
            aGO += (floatx2){bg + b2f(gp.y & 0xffffu), bo + b2f(gp.y >> 16)};
        }
        // butterfly across the 4 q-lanes (lane bits 4,5): all lanes -> full sums
        float ai = aIF[0], af = aIF[1], ag = aGO[0], ao = aGO[1];
        ai += __shfl_xor(ai, 16, 64); af += __shfl_xor(af, 16, 64);
        ag += __shfl_xor(ag, 16, 64); ao += __shfl_xor(ao, 16, 64);
        ai += __shfl_xor(ai, 32, 64); af += __shfl_xor(af, 32, 64);
        ag += __shfl_xor(ag, 32, 64); ao += __shfl_xor(ao, 32, 64);
        // epilogue on ALL lanes (redundant across q; c stays identical)
        float ii = sigm_(ai);
        float ff = sigm_(af);
        float gg = tanh_(ag);
        float oo = sigm_(ao);
        c = ff * c + ii * gg;
        float h = oo * tanh_(c);
        if (q == 0) {
            hsbuf[p ^ 1][(j >> 6) * 68 + (j & 63)] = h * 0.0625f;
            Hout[((long)(b * TT + tt)) * 512 + dir * HH + j] = __float2bfloat16(h);
        }
        p ^= 1;
        // LDS-only wait + builtin barrier (no vmcnt drain -> Hout stores fly)
        asm volatile("s_waitcnt lgkmcnt(0)" ::: "memory");
        __builtin_amdgcn_s_barrier();
    }
}

// ---------------- emissions: E[row][l] = h[row][0..511] . Wlin[l][0..511] + blin[l] ----------------
__global__ void k_emis(const __hip_bfloat16* __restrict__ Hc,   // [MROWS][512]
                       const float* __restrict__ Wlin,          // [15][512] fp32
                       const float* __restrict__ blin,
                       float* __restrict__ E) {
    int gid = blockIdx.x * blockDim.x + threadIdx.x;
    if (gid >= MROWS * LL) return;
    int row = gid / LL;
    int l = gid - row * LL;
    const __hip_bfloat16* hr = Hc + (long)row * 512;
    const float* wr = Wlin + l * 512;
    float s = blin[l];
    #pragma unroll 8
    for (int k = 0; k < 512; ++k)
        s = fmaf(__bfloat162float(hr[k]), wr[k], s);
    E[gid] = s;
}

// ---------------- CRF NLL per batch: one wave per batch ----------------
__global__ void k_crf(const float* __restrict__ E,      // [B][T][15]
                      const int* __restrict__ tags,     // [B][T]
                      const int* __restrict__ lengths,
                      const float* __restrict__ start_t,
                      const float* __restrict__ end_t,
                      const float* __restrict__ trans,  // [15][15] fp32
                      float* __restrict__ outp) {
    int b = blockIdx.x;
    int lane = threadIdx.x;
    int len = lengths[b];
    const float* Eb = E + (long)b * TT * LL;
    const int* tg = tags + b * TT;
    float tcol[LL];
    #pragma unroll
    for (int k = 0; k < LL; ++k)
        tcol[k] = (lane < LL) ? trans[k * LL + lane] : 0.f;
    float alpha = (lane < LL) ? start_t[lane] + Eb[lane] : -1e30f;
    for (int t = 1; t < len; ++t) {
        float e = (lane < LL) ? Eb[t * LL + lane] : 0.f;
        float m = -1e30f;
        float v[LL];
        #pragma unroll
        for (int k = 0; k < LL; ++k) {
            float ak = __shfl(alpha, k, 64);
            v[k] = ak + tcol[k];
            m = fmaxf(m, v[k]);
        }
        float s = 0.f;
        #pragma unroll
        for (int k = 0; k < LL; ++k) s += __expf(v[k] - m);
        alpha = m + __logf(s) + e;
    }
    // denominator
    float z = alpha + ((lane < LL) ? end_t[lane] : -1e30f);
    float m2 = -1e30f;
    #pragma unroll
    for (int k = 0; k < LL; ++k) m2 = fmaxf(m2, __shfl(z, k, 64));
    float s2 = 0.f;
    #pragma unroll
    for (int k = 0; k < LL; ++k) s2 += __expf(__shfl(z, k, 64) - m2);
    float den = m2 + __logf(s2);
    // numerator (lane-parallel over t, then wave-reduce)
    float part = 0.f;
    for (int t = lane; t < TT; t += 64) {
        if (t < len) {
            int tag = tg[t];
            part += Eb[t * LL + tag];
            if (t >= 1) part += trans[tg[t - 1] * LL + tag];
        }
    }
    #pragma unroll
    for (int off = 32; off > 0; off >>= 1) part += __shfl_down(part, off, 64);
    if (lane == 0) {
        float num = part + start_t[tg[0]] + end_t[tg[len - 1]];
        outp[b] = num - den;
    }
}

// output is float32 (reference output dtype)
__global__ void k_final(const float* __restrict__ outp, float* __restrict__ out) {
    int lane = threadIdx.x;
    float v = outp[lane];
    #pragma unroll
    for (int off = 32; off > 0; off >>= 1) v += __shfl_down(v, off, 64);
    if (lane == 0) out[0] = -v;   // loss = -sum(num - den)
}

// ---------------- launch ----------------
extern "C" void kernel_launch(void* const* d_in, const int* in_sizes, int n_in,
                              void* d_out, int out_size, void* d_ws, size_t ws_size,
                              hipStream_t stream) {
    const int* input_ids    = (const int*)d_in[0];
    const int* lengths      = (const int*)d_in[1];
    const int* softword_ids = (const int*)d_in[2];
    const int* label_ids    = (const int*)d_in[3];
    const float* emb      = (const float*)d_in[4];
    const float* soft_emb = (const float*)d_in[5];
    const float* Wih_f = (const float*)d_in[6];
    const float* Whh_f = (const float*)d_in[7];
    const float* bih_f = (const float*)d_in[8];
    const float* bhh_f = (const float*)d_in[9];
    const float* Wih_b = (const float*)d_in[10];
    const float* Whh_b = (const float*)d_in[11];
    const float* bih_b = (const float*)d_in[12];
    const float* bhh_b = (const float*)d_in[13];
    const float* Wlin  = (const float*)d_in[14];
    const float* blin  = (const float*)d_in[15];
    const float* start_t = (const float*)d_in[16];
    const float* end_t   = (const float*)d_in[17];
    const float* trans   = (const float*)d_in[18];

    // workspace layout, small buffers first (all offsets 256B aligned)
    char* base = (char*)d_ws;
    float*          part = (float*)(base);                             // 64*4          =        256
    float*          bias = (float*)(base + 256);                       // 2*1024*4      =      8,192
    float*          E    = (float*)(base + 8448);                      // 16384*15*4    =    983,040
    unsigned int*   Wpk8 = (unsigned int*)(base + 991488);             // 2*4*256*64*4  =    524,288 (region reserves 1 MB)
    __hip_bfloat16* Wcat = (__hip_bfloat16*)(base + 2040064);          // 2048*608*2    =  2,490,368
    __hip_bfloat16* Hc   = (__hip_bfloat16*)(base + 4530432);          // 64*256*512*2  = 16,777,216
    __hip_bfloat16* X    = (__hip_bfloat16*)(base + 21307648);         // 16384*608*2   = 19,922,944
    __hip_bfloat16* G    = (__hip_bfloat16*)(base + 41230592);         // 16384*2048*2  = 67,108,864
                                                                       // end: 108,339,456

    k_embed<<<MROWS, 64, 0, stream>>>(input_ids, softword_ids, emb, soft_emb, X);
    k_wcat<<<NG, 64, 0, stream>>>(Wih_f, Wih_b, Wcat);
    k_wpk<<<512, 256, 0, stream>>>(Whh_f, Whh_b, Wpk8);
    k_bias<<<8, 256, 0, stream>>>(bih_f, bhh_f, bih_b, bhh_b, bias);
    k_gemm<<<dim3(MROWS / 128, NG / 128), 256, 0, stream>>>(X, Wcat, G);
    k_lstm<<<BB * 2, 1024, 0, stream>>>(G, Wpk8, bias, lengths, Hc);
    k_emis<<<(MROWS * LL) / 256, 256, 0, stream>>>(Hc, Wlin, blin, E);
    k_crf<<<BB, 64, 0, stream>>>(E, label_ids, lengths, start_t, end_t, trans, part);
    k_final<<<1, 64, 0, stream>>>(part, (float*)d_out);
}